// Round 2
// baseline (280.988 us; speedup 1.0000x reference)
//
#include <hip/hip_runtime.h>
#include <hip/hip_bf16.h>

typedef __attribute__((ext_vector_type(8))) short bf16x8;
typedef __attribute__((ext_vector_type(4))) float f32x4;
typedef __attribute__((ext_vector_type(8))) unsigned short u16x8;

__device__ __forceinline__ unsigned short f2bf(float f) {
  union { float f; unsigned u; } c; c.f = f;
  unsigned u = c.u;
  u = (u + 0x7FFFu + ((u >> 16) & 1u)) >> 16;   // RNE
  return (unsigned short)u;
}

__device__ __forceinline__ void gld_lds16(const void* g, void* l) {
  __builtin_amdgcn_global_load_lds(
      (__attribute__((address_space(1))) unsigned int*)g,
      (__attribute__((address_space(3))) unsigned int*)l,
      16, 0, 0);
}

// ---------------- conversion kernels ----------------

// blocks [0, nx/2048):            x  -> x16   (8 elems/thread)
// blocks [nx/2048, +nk/2048):     K  -> K16
// first 32 blocks also zero lsum[8192]
__global__ void cvt_all(const float* __restrict__ x, unsigned short* __restrict__ x16,
                        const float* __restrict__ Kw, unsigned short* __restrict__ K16,
                        float* __restrict__ lsum) {
  const int xblocks = 4096;  // 8M elems / 2048
  int b = blockIdx.x;
  if (b < 32) lsum[b * 256 + threadIdx.x] = 0.f;
  const float* in;
  unsigned short* out;
  int i;
  if (b < xblocks) {
    in = x; out = x16; i = (b * 256 + threadIdx.x) * 8;
  } else {
    in = Kw; out = K16; i = ((b - xblocks) * 256 + threadIdx.x) * 8;
  }
  const float4* p = (const float4*)(in + i);
  float4 a = p[0], bb = p[1];
  u16x8 r;
  r[0] = f2bf(a.x); r[1] = f2bf(a.y); r[2] = f2bf(a.z); r[3] = f2bf(a.w);
  r[4] = f2bf(bb.x); r[5] = f2bf(bb.y); r[6] = f2bf(bb.z); r[7] = f2bf(bb.w);
  *(u16x8*)(out + i) = r;
}

// V [4096,1024] fp32 -> Vt [1024,4096] bf16
__global__ void transpose_cvt(const float* __restrict__ V,
                              unsigned short* __restrict__ Vt) {
  __shared__ unsigned short t[64][65];
  const int p0 = blockIdx.x * 64;
  const int e0 = blockIdx.y * 64;
  const int tx = threadIdx.x & 63;
  const int ty = threadIdx.x >> 6;
#pragma unroll
  for (int i = 0; i < 16; ++i) {
    int p = ty + i * 4;
    t[p][tx] = f2bf(V[(size_t)(p0 + p) * 1024 + e0 + tx]);
  }
  __syncthreads();
#pragma unroll
  for (int i = 0; i < 16; ++i) {
    int e = ty + i * 4;
    Vt[(size_t)(e0 + e) * 4096 + p0 + tx] = t[tx][e];
  }
}

// ---------------- NT GEMM, 128x128 tile, BK=64, bf16 MFMA ----------------
// A [M x Kd] row-major bf16, B [N x Kd] row-major bf16 (i.e. B^T input).
// EPI==0: C = exp2(scale*A.B^T) -> Pout (bf16) + atomic row sums -> lsum
// EPI==1: C = (A.B^T) * (1/lin[row]) -> Cout (fp32)
template <int EPI>
__global__ __launch_bounds__(256) void gemm_nt(
    const unsigned short* __restrict__ A, const unsigned short* __restrict__ B,
    int M, int N, int Kd,
    unsigned short* __restrict__ Pout, float* __restrict__ lsum,
    float* __restrict__ Cout, const float* __restrict__ lin, float scale) {
  __shared__ __align__(16) unsigned short sA[128 * 64];
  __shared__ __align__(16) unsigned short sB[128 * 64];

  const int tid = threadIdx.x;
  const int lane = tid & 63;
  const int w = tid >> 6;
  const int wm = w >> 1;
  const int wn = w & 1;
  const int row0 = blockIdx.y * 128;
  const int col0 = blockIdx.x * 128;

  f32x4 acc[4][4] = {};

  // Staging: 1024 16B-chunks per tile; chunk c -> row=c>>3, slot=c&7.
  // XOR swizzle: LDS slot s of row r holds global chunk s^(r&7).
  // Precompute global pointers once; advance by 64 elems (128 B) per iter.
  const unsigned short* pA[4];
  const unsigned short* pB[4];
  char* ldsA[4];
  char* ldsB[4];
#pragma unroll
  for (int j = 0; j < 4; ++j) {
    int c = j * 256 + tid;
    int r = c >> 3;
    int cs = (c & 7) ^ (r & 7);
    pA[j] = A + (size_t)(row0 + r) * Kd + cs * 8;
    pB[j] = B + (size_t)(col0 + r) * Kd + cs * 8;
    int off = (j * 256 + (w << 6)) * 16;  // wave-uniform byte base
    ldsA[j] = (char*)sA + off;
    ldsB[j] = (char*)sB + off;
  }

  // Fragment LDS addressing: r = w?*64 + mi*16 + ml, so r&7 == ml&7 and the
  // XOR-swizzled byte address = base_ks + mi*2048 (imm offset).
  const int q = lane >> 4;
  const int ml = lane & 15;
  const char* fA[2];
  const char* fB[2];
#pragma unroll
  for (int ks = 0; ks < 2; ++ks) {
    int cc = (ks * 4 + q) ^ (ml & 7);
    fA[ks] = (const char*)sA + (wm * 64 + ml) * 128 + cc * 16;
    fB[ks] = (const char*)sB + (wn * 64 + ml) * 128 + cc * 16;
  }

  const int kIters = Kd >> 6;
  for (int it = 0; it < kIters; ++it) {
    __syncthreads();
#pragma unroll
    for (int j = 0; j < 4; ++j) {
      gld_lds16(pA[j], ldsA[j]);
      gld_lds16(pB[j], ldsB[j]);
      pA[j] += 64;
      pB[j] += 64;
    }
    __syncthreads();

#pragma unroll
    for (int ks = 0; ks < 2; ++ks) {
      bf16x8 af[4], bfr[4];
#pragma unroll
      for (int mi = 0; mi < 4; ++mi) af[mi] = *(const bf16x8*)(fA[ks] + mi * 2048);
#pragma unroll
      for (int ni = 0; ni < 4; ++ni) bfr[ni] = *(const bf16x8*)(fB[ks] + ni * 2048);
#pragma unroll
      for (int mi = 0; mi < 4; ++mi)
#pragma unroll
        for (int ni = 0; ni < 4; ++ni)
          acc[mi][ni] = __builtin_amdgcn_mfma_f32_16x16x32_bf16(
              af[mi], bfr[ni], acc[mi][ni], 0, 0, 0);
    }
  }

  if constexpr (EPI == 0) {
#pragma unroll
    for (int mi = 0; mi < 4; ++mi) {
#pragma unroll
      for (int j = 0; j < 4; ++j) {
        int gr = row0 + wm * 64 + mi * 16 + q * 4 + j;
        float rsum = 0.f;
#pragma unroll
        for (int ni = 0; ni < 4; ++ni) {
          int gc = col0 + wn * 64 + ni * 16 + ml;
          float p = exp2f(acc[mi][ni][j] * scale);  // scale includes log2(e)
          rsum += p;
          Pout[(size_t)gr * N + gc] = f2bf(p);
        }
        rsum += __shfl_xor(rsum, 1);
        rsum += __shfl_xor(rsum, 2);
        rsum += __shfl_xor(rsum, 4);
        rsum += __shfl_xor(rsum, 8);
        if (ml == 0) atomicAdd(&lsum[gr], rsum);
      }
    }
  } else {
#pragma unroll
    for (int mi = 0; mi < 4; ++mi) {
#pragma unroll
      for (int j = 0; j < 4; ++j) {
        int gr = row0 + wm * 64 + mi * 16 + q * 4 + j;
        float rl = 1.0f / lin[gr];
#pragma unroll
        for (int ni = 0; ni < 4; ++ni) {
          int gc = col0 + wn * 64 + ni * 16 + ml;
          Cout[(size_t)gr * N + gc] = acc[mi][ni][j] * rl;
        }
      }
    }
  }
}

extern "C" void kernel_launch(void* const* d_in, const int* in_sizes, int n_in,
                              void* d_out, int out_size, void* d_ws,
                              size_t ws_size, hipStream_t stream) {
  const float* x = (const float*)d_in[0];   // [8192,1024]
  const float* Kw = (const float*)d_in[1];  // [4096,1024]
  const float* Vw = (const float*)d_in[2];  // [4096,1024]
  float* out = (float*)d_out;               // [8192,1024]
  char* ws = (char*)d_ws;

  unsigned short* x16  = (unsigned short*)(ws);                   // 16 MB
  unsigned short* K16  = (unsigned short*)(ws + (16u << 20));     //  8 MB
  unsigned short* V16t = (unsigned short*)(ws + (24u << 20));     //  8 MB
  float*          lsum = (float*)(ws + (32u << 20));              // 32 KB
  unsigned short* P16  = (unsigned short*)(ws + (33u << 20));     // 64 MB

  cvt_all<<<4096 + 2048, 256, 0, stream>>>(x, x16, Kw, K16, lsum);
  transpose_cvt<<<dim3(64, 16), 256, 0, stream>>>(Vw, V16t);

  // GEMM1: P = exp(x16 . K16^T / 32), row sums -> lsum.
  // scale = (1/32) * log2(e) so epilogue is one v_mul + v_exp.
  gemm_nt<0><<<dim3(32, 64), 256, 0, stream>>>(
      x16, K16, 8192, 4096, 1024, P16, lsum, nullptr, nullptr,
      0.03125f * 1.44269504088896340736f);
  // GEMM2: out = (P16 . V16t^T) / lsum[row]
  gemm_nt<1><<<dim3(8, 64), 256, 0, stream>>>(
      P16, V16t, 8192, 1024, 4096, nullptr, nullptr, out, lsum, 1.0f);
}

// Round 3
// 268.393 us; speedup vs baseline: 1.0469x; 1.0469x over previous
//
#include <hip/hip_runtime.h>
#include <hip/hip_bf16.h>

typedef __attribute__((ext_vector_type(8))) short bf16x8;
typedef __attribute__((ext_vector_type(4))) float f32x4;
typedef __attribute__((ext_vector_type(8))) unsigned short u16x8;

__device__ __forceinline__ unsigned short f2bf(float f) {
  union { float f; unsigned u; } c; c.f = f;
  unsigned u = c.u;
  u = (u + 0x7FFFu + ((u >> 16) & 1u)) >> 16;   // RNE
  return (unsigned short)u;
}

__device__ __forceinline__ void gld_lds16(const void* g, void* l) {
  __builtin_amdgcn_global_load_lds(
      (__attribute__((address_space(1))) unsigned int*)g,
      (__attribute__((address_space(3))) unsigned int*)l,
      16, 0, 0);
}

// ---------------- single fused conversion kernel ----------------
// blocks [0,4096):       x  -> x16  (8 elems/thread, 2048/block)
// blocks [4096,6144):    K  -> K16
// blocks [6144,7168):    V [4096,1024] -> Vt [1024,4096] (64x64 tiles)
// first 32 blocks also zero lsum[8192]
__global__ void cvt_all(const float* __restrict__ x, unsigned short* __restrict__ x16,
                        const float* __restrict__ Kw, unsigned short* __restrict__ K16,
                        const float* __restrict__ V, unsigned short* __restrict__ Vt,
                        float* __restrict__ lsum) {
  const int b = blockIdx.x;
  if (b < 32) lsum[b * 256 + threadIdx.x] = 0.f;

  if (b < 6144) {
    const float* in;
    unsigned short* out;
    int i;
    if (b < 4096) {
      in = x; out = x16; i = (b * 256 + threadIdx.x) * 8;
    } else {
      in = Kw; out = K16; i = ((b - 4096) * 256 + threadIdx.x) * 8;
    }
    const float4* p = (const float4*)(in + i);
    float4 a = p[0], bb = p[1];
    u16x8 r;
    r[0] = f2bf(a.x); r[1] = f2bf(a.y); r[2] = f2bf(a.z); r[3] = f2bf(a.w);
    r[4] = f2bf(bb.x); r[5] = f2bf(bb.y); r[6] = f2bf(bb.z); r[7] = f2bf(bb.w);
    *(u16x8*)(out + i) = r;
  } else {
    __shared__ unsigned short t[64][65];
    const int tile = b - 6144;
    const int p0 = (tile & 63) * 64;
    const int e0 = (tile >> 6) * 64;
    const int tx = threadIdx.x & 63;
    const int ty = threadIdx.x >> 6;
#pragma unroll
    for (int i = 0; i < 16; ++i) {
      int p = ty + i * 4;
      t[p][tx] = f2bf(V[(size_t)(p0 + p) * 1024 + e0 + tx]);
    }
    __syncthreads();
#pragma unroll
    for (int i = 0; i < 16; ++i) {
      int e = ty + i * 4;
      Vt[(size_t)(e0 + e) * 4096 + p0 + tx] = t[tx][e];
    }
  }
}

// ---------------- NT GEMM, 128x128 tile, BK=64, bf16 MFMA ----------------
// A [M x Kd] row-major bf16, B [N x Kd] row-major bf16 (i.e. B^T input).
// EPI==0: C = exp2(scale*A.B^T) -> Pout (bf16) + atomic row sums -> lsum
//         2D grid (x = N-tiles, y = M-tiles)
// EPI==1: C = (A.B^T) * (1/lin[row]) -> Cout (fp32)
//         1D grid, XCD-swizzled: bid = (m%8) + 8*(n + 8*(m/8)) so the 8
//         N-blocks sharing a P row-strip land on one XCD (bid%8 heuristic).
template <int EPI>
__global__ __launch_bounds__(256) void gemm_nt(
    const unsigned short* __restrict__ A, const unsigned short* __restrict__ B,
    int M, int N, int Kd,
    unsigned short* __restrict__ Pout, float* __restrict__ lsum,
    float* __restrict__ Cout, const float* __restrict__ lin, float scale) {
  __shared__ __align__(16) unsigned short sA[128 * 64];
  __shared__ __align__(16) unsigned short sB[128 * 64];

  const int tid = threadIdx.x;
  const int lane = tid & 63;
  const int w = tid >> 6;
  const int wm = w >> 1;
  const int wn = w & 1;

  int row0, col0;
  if constexpr (EPI == 0) {
    row0 = blockIdx.y * 128;
    col0 = blockIdx.x * 128;
  } else {
    // decode XCD swizzle: m = (bid/64)*8 + bid%8 ; n = (bid/8)%8
    int bid = blockIdx.x;
    row0 = (((bid >> 6) << 3) | (bid & 7)) * 128;
    col0 = ((bid >> 3) & 7) * 128;
  }

  f32x4 acc[4][4] = {};

  // Staging: 1024 16B-chunks per tile; chunk c -> row=c>>3, slot=c&7.
  // XOR swizzle: LDS slot s of row r holds global chunk s^(r&7).
  const unsigned short* pA[4];
  const unsigned short* pB[4];
  char* ldsA[4];
  char* ldsB[4];
#pragma unroll
  for (int j = 0; j < 4; ++j) {
    int c = j * 256 + tid;
    int r = c >> 3;
    int cs = (c & 7) ^ (r & 7);
    pA[j] = A + (size_t)(row0 + r) * Kd + cs * 8;
    pB[j] = B + (size_t)(col0 + r) * Kd + cs * 8;
    int off = (j * 256 + (w << 6)) * 16;  // wave-uniform byte base
    ldsA[j] = (char*)sA + off;
    ldsB[j] = (char*)sB + off;
  }

  // Fragment LDS addressing: r = w?*64 + mi*16 + ml, so r&7 == ml&7 and the
  // XOR-swizzled byte address = base_ks + mi*2048 (imm offset).
  const int q = lane >> 4;
  const int ml = lane & 15;
  const char* fA[2];
  const char* fB[2];
#pragma unroll
  for (int ks = 0; ks < 2; ++ks) {
    int cc = (ks * 4 + q) ^ (ml & 7);
    fA[ks] = (const char*)sA + (wm * 64 + ml) * 128 + cc * 16;
    fB[ks] = (const char*)sB + (wn * 64 + ml) * 128 + cc * 16;
  }

  const int kIters = Kd >> 6;
  for (int it = 0; it < kIters; ++it) {
    __syncthreads();
#pragma unroll
    for (int j = 0; j < 4; ++j) {
      gld_lds16(pA[j], ldsA[j]);
      gld_lds16(pB[j], ldsB[j]);
      pA[j] += 64;
      pB[j] += 64;
    }
    __syncthreads();

#pragma unroll
    for (int ks = 0; ks < 2; ++ks) {
      bf16x8 af[4], bfr[4];
#pragma unroll
      for (int mi = 0; mi < 4; ++mi) af[mi] = *(const bf16x8*)(fA[ks] + mi * 2048);
#pragma unroll
      for (int ni = 0; ni < 4; ++ni) bfr[ni] = *(const bf16x8*)(fB[ks] + ni * 2048);
#pragma unroll
      for (int mi = 0; mi < 4; ++mi)
#pragma unroll
        for (int ni = 0; ni < 4; ++ni)
          acc[mi][ni] = __builtin_amdgcn_mfma_f32_16x16x32_bf16(
              af[mi], bfr[ni], acc[mi][ni], 0, 0, 0);
    }
  }

  if constexpr (EPI == 0) {
#pragma unroll
    for (int mi = 0; mi < 4; ++mi) {
#pragma unroll
      for (int j = 0; j < 4; ++j) {
        int gr = row0 + wm * 64 + mi * 16 + q * 4 + j;
        float rsum = 0.f;
#pragma unroll
        for (int ni = 0; ni < 4; ++ni) {
          int gc = col0 + wn * 64 + ni * 16 + ml;
          float p = exp2f(acc[mi][ni][j] * scale);  // scale includes log2(e)
          rsum += p;
          Pout[(size_t)gr * N + gc] = f2bf(p);
        }
        rsum += __shfl_xor(rsum, 1);
        rsum += __shfl_xor(rsum, 2);
        rsum += __shfl_xor(rsum, 4);
        rsum += __shfl_xor(rsum, 8);
        if (ml == 0) atomicAdd(&lsum[gr], rsum);
      }
    }
  } else {
#pragma unroll
    for (int mi = 0; mi < 4; ++mi) {
#pragma unroll
      for (int j = 0; j < 4; ++j) {
        int gr = row0 + wm * 64 + mi * 16 + q * 4 + j;
        float rl = 1.0f / lin[gr];
#pragma unroll
        for (int ni = 0; ni < 4; ++ni) {
          int gc = col0 + wn * 64 + ni * 16 + ml;
          Cout[(size_t)gr * N + gc] = acc[mi][ni][j] * rl;
        }
      }
    }
  }
}

extern "C" void kernel_launch(void* const* d_in, const int* in_sizes, int n_in,
                              void* d_out, int out_size, void* d_ws,
                              size_t ws_size, hipStream_t stream) {
  const float* x = (const float*)d_in[0];   // [8192,1024]
  const float* Kw = (const float*)d_in[1];  // [4096,1024]
  const float* Vw = (const float*)d_in[2];  // [4096,1024]
  float* out = (float*)d_out;               // [8192,1024]
  char* ws = (char*)d_ws;

  unsigned short* x16  = (unsigned short*)(ws);                   // 16 MB
  unsigned short* K16  = (unsigned short*)(ws + (16u << 20));     //  8 MB
  unsigned short* V16t = (unsigned short*)(ws + (24u << 20));     //  8 MB
  float*          lsum = (float*)(ws + (32u << 20));              // 32 KB
  unsigned short* P16  = (unsigned short*)(ws + (33u << 20));     // 64 MB

  cvt_all<<<7168, 256, 0, stream>>>(x, x16, Kw, K16, Vw, V16t, lsum);

  // GEMM1: P = exp(x16 . K16^T / 32), row sums -> lsum.
  // scale = (1/32) * log2(e) so epilogue is one v_mul + v_exp.
  gemm_nt<0><<<dim3(32, 64), 256, 0, stream>>>(
      x16, K16, 8192, 4096, 1024, P16, lsum, nullptr, nullptr,
      0.03125f * 1.44269504088896340736f);
  // GEMM2: out = (P16 . V16t^T) / lsum[row], XCD-swizzled 1D grid
  gemm_nt<1><<<512, 256, 0, stream>>>(
      P16, V16t, 8192, 1024, 4096, nullptr, nullptr, out, lsum, 1.0f);
}